// Round 1
// baseline (198.710 us; speedup 1.0000x reference)
//
#include <hip/hip_runtime.h>
#include <hip/hip_bf16.h>
#include <stdint.h>

#define N_DIM 1024
#define DEPTH 2
#define ABCD_TOTAL 4092   // 2*(1024+512+...+2)

typedef __attribute__((ext_vector_type(8))) short short8;   // 8 bf16 (4 VGPRs)
typedef __attribute__((ext_vector_type(4))) float floatx4;  // MFMA accumulator

// ---------------------------------------------------------------------------
// Kernel 1: build W^T (bf16) by running the (linear) butterfly pipeline on the
// identity matrix. Block i processes basis row e_i; final real part of h is
// W[i, :], stored transposed: Wt[j*1024 + i] so the GEMM's B operand reads
// contiguous-K rows.
// ---------------------------------------------------------------------------
__global__ __launch_bounds__(256) void build_w(
    const float* __restrict__ perm_logit,  // (2,3)
    const float* __restrict__ abcd,        // (2,4092,2)
    __hip_bfloat16* __restrict__ Wt)       // (1024 n, 1024 k)
{
    const int row = blockIdx.x;
    const int tid = threadIdx.x;
    __shared__ float2 h[2][N_DIM];  // ping-pong complex buffers, 16 KB

    for (int j = tid; j < N_DIM; j += 256)
        h[0][j] = make_float2(j == row ? 1.0f : 0.0f, 0.0f);
    __syncthreads();

    int cur = 0;
    for (int d = 0; d < DEPTH; ++d) {
        const float p0 = 1.0f / (1.0f + expf(-perm_logit[d * 3 + 0]));
        const float p1 = 1.0f / (1.0f + expf(-perm_logit[d * 3 + 1]));
        const float p2 = 1.0f / (1.0f + expf(-perm_logit[d * 3 + 2]));

        // ---- perm factors, m = 4 .. 1024 ----
        for (int s = 2; s <= 10; ++s) {
            const int m = 1 << s, half = m >> 1, hq = half >> 1;
            const float2* __restrict__ in  = h[cur];
            float2* __restrict__ out       = h[cur ^ 1];
            // 512 mirror-pairs per row; each pair shares both s1 values.
            for (int t = tid; t < 512; t += 256) {
                const int blk = t >> (s - 1);
                const int r   = t & (half - 1);
                const int base = blk * m;
                int q1, q2; float pc;
                if (r < hq) { q1 = r;            q2 = half - 1 - r;        pc = p1; }
                else        { int r2 = r - hq;   q1 = half + r2;
                              q2 = 2 * half - 1 - r2;                      pc = p2; }
                // s1(q) = (1-p0)*in[q] + p0*in[eo_src(q)]
                const int src1 = (q1 < half) ? 2 * q1 : 2 * (q1 - half) + 1;
                const int src2 = (q2 < half) ? 2 * q2 : 2 * (q2 - half) + 1;
                float2 b1 = in[base + q1], a1 = in[base + src1];
                float2 b2 = in[base + q2], a2 = in[base + src2];
                float2 s1a, s1b, o1, o2;
                s1a.x = b1.x + p0 * (a1.x - b1.x);  s1a.y = b1.y + p0 * (a1.y - b1.y);
                s1b.x = b2.x + p0 * (a2.x - b2.x);  s1b.y = b2.y + p0 * (a2.y - b2.y);
                o1.x = s1a.x + pc * (s1b.x - s1a.x); o1.y = s1a.y + pc * (s1b.y - s1a.y);
                o2.x = s1b.x + pc * (s1a.x - s1b.x); o2.y = s1b.y + pc * (s1a.y - s1b.y);
                out[base + q1] = o1;
                out[base + q2] = o2;
            }
            __syncthreads();
            cur ^= 1;
        }

        // ---- diag factors, m = 2 .. 1024 ----
        for (int s = 1; s <= 10; ++s) {
            const int m = 1 << s, half = m >> 1;
            const int off = 4096 - 4 * m;  // offset of this factor's ABCD block
            const float* __restrict__ ab = abcd + (size_t)d * (ABCD_TOTAL * 2) + (size_t)off * 2;
            const float2* __restrict__ in = h[cur];
            float2* __restrict__ out      = h[cur ^ 1];
            for (int t = tid; t < 512; t += 256) {
                const int blk = t >> (s - 1);
                const int k   = t & (half - 1);
                const int base = blk * m;
                float2 xt = in[base + k];
                float2 xb = in[base + half + k];
                float2 A  = *(const float2*)(ab + 2 * (size_t)k);
                float2 Bc = *(const float2*)(ab + 2 * (size_t)(half + k));
                float2 Cc = *(const float2*)(ab + 2 * (size_t)(m + k));
                float2 Dc = *(const float2*)(ab + 2 * (size_t)(m + half + k));
                float2 yt, yb;
                yt.x = A.x * xt.x - A.y * xt.y + Bc.x * xb.x - Bc.y * xb.y;
                yt.y = A.x * xt.y + A.y * xt.x + Bc.x * xb.y + Bc.y * xb.x;
                yb.x = Cc.x * xt.x - Cc.y * xt.y + Dc.x * xb.x - Dc.y * xb.y;
                yb.y = Cc.x * xt.y + Cc.y * xt.x + Dc.x * xb.y + Dc.y * xb.x;
                out[base + k]        = yt;
                out[base + half + k] = yb;
            }
            __syncthreads();
            cur ^= 1;
        }
    }

    // Real part of final h is W[row, :]; store transposed (bf16).
    for (int j = tid; j < N_DIM; j += 256)
        Wt[(size_t)j * N_DIM + row] = __float2bfloat16(h[cur][j].x);
}

// ---------------------------------------------------------------------------
// Kernel 2: cast x (fp32) -> bf16, 8 elements/thread.
// ---------------------------------------------------------------------------
__global__ __launch_bounds__(256) void cast_x(
    const float* __restrict__ x, __hip_bfloat16* __restrict__ xb)
{
    const size_t i = ((size_t)blockIdx.x * 256 + threadIdx.x) * 8;
    float4 v0 = *(const float4*)(x + i);
    float4 v1 = *(const float4*)(x + i + 4);
    union { __hip_bfloat16 h[8]; int4 v; } u;
    u.h[0] = __float2bfloat16(v0.x); u.h[1] = __float2bfloat16(v0.y);
    u.h[2] = __float2bfloat16(v0.z); u.h[3] = __float2bfloat16(v0.w);
    u.h[4] = __float2bfloat16(v1.x); u.h[5] = __float2bfloat16(v1.y);
    u.h[6] = __float2bfloat16(v1.z); u.h[7] = __float2bfloat16(v1.w);
    *(int4*)(xb + i) = u.v;
}

// ---------------------------------------------------------------------------
// Kernel 3: out = A(16384x1024 bf16) @ W + bias, fp32 out.
// m97-style: 128x128 tile, BK=32, 256 threads (2x2 waves, 64x64 each),
// global_load_lds width 16, 16x16x32 bf16 MFMA, 4x4 accs/wave.
// B operand is Wt (n-major, contiguous K) so frag reads are ds_read_b128.
// ---------------------------------------------------------------------------
#define BM 128
#define BN 128
#define BK 32

__device__ __forceinline__ void gl_lds16(const void* g, void* l) {
    __builtin_amdgcn_global_load_lds(
        (const __attribute__((address_space(1))) uint32_t*)g,
        (__attribute__((address_space(3))) uint32_t*)l, 16, 0, 0);
}

__global__ __launch_bounds__(256) void gemm_bt(
    const __hip_bfloat16* __restrict__ A,   // (16384, 1024)
    const __hip_bfloat16* __restrict__ Bt,  // (1024 n, 1024 k)
    const float* __restrict__ bias,         // (1024)
    float* __restrict__ C)                  // (16384, 1024)
{
    const int tid = threadIdx.x;
    const int bx  = blockIdx.x;       // 1024 blocks: 128 m-tiles x 8 n-tiles
    const int m0  = (bx >> 3) * BM;
    const int n0  = (bx & 7) * BN;

    __shared__ __hip_bfloat16 sA[BM * BK];  // 8 KB
    __shared__ __hip_bfloat16 sB[BN * BK];  // 8 KB

    const int lane = tid & 63;
    const int wm   = ((tid >> 6) & 1) * 64;   // wave row offset in tile
    const int wn   = ((tid >> 6) >> 1) * 64;  // wave col offset in tile
    const int lrow = lane & 15;               // m (A) / n (B) / col (D)
    const int lq   = lane >> 4;               // quad: k-group / D row group

    // staging: granule g in [0,512): row = g>>2 (of 128), 16B chunk c = g&3
    const int r1 = tid >> 2, c1 = tid & 3;

    floatx4 acc[4][4] = {};

    for (int kt = 0; kt < 32; ++kt) {
        const int k0 = kt * BK;
        gl_lds16(A  + (size_t)(m0 + r1)      * N_DIM + k0 + c1 * 8, (char*)sA + tid * 16);
        gl_lds16(A  + (size_t)(m0 + 64 + r1) * N_DIM + k0 + c1 * 8, (char*)sA + (tid + 256) * 16);
        gl_lds16(Bt + (size_t)(n0 + r1)      * N_DIM + k0 + c1 * 8, (char*)sB + tid * 16);
        gl_lds16(Bt + (size_t)(n0 + 64 + r1) * N_DIM + k0 + c1 * 8, (char*)sB + (tid + 256) * 16);
        __syncthreads();

        short8 af[4], bf[4];
#pragma unroll
        for (int i = 0; i < 4; ++i) {
            af[i] = *(const short8*)(sA + (wm + i * 16 + lrow) * BK + lq * 8);
            bf[i] = *(const short8*)(sB + (wn + i * 16 + lrow) * BK + lq * 8);
        }
#pragma unroll
        for (int i = 0; i < 4; ++i)
#pragma unroll
            for (int j = 0; j < 4; ++j)
                acc[i][j] = __builtin_amdgcn_mfma_f32_16x16x32_bf16(
                    af[i], bf[j], acc[i][j], 0, 0, 0);
        __syncthreads();
    }

    // epilogue: D[row=lq*4+r][col=lrow] per 16x16 tile, + bias
#pragma unroll
    for (int j = 0; j < 4; ++j) {
        const int gn = n0 + wn + j * 16 + lrow;
        const float bv = bias[gn];
#pragma unroll
        for (int i = 0; i < 4; ++i) {
            const int gm = m0 + wm + i * 16 + lq * 4;
#pragma unroll
            for (int r = 0; r < 4; ++r)
                C[(size_t)(gm + r) * N_DIM + gn] = acc[i][j][r] + bv;
        }
    }
}

// ---------------------------------------------------------------------------
extern "C" void kernel_launch(void* const* d_in, const int* in_sizes, int n_in,
                              void* d_out, int out_size, void* d_ws, size_t ws_size,
                              hipStream_t stream) {
    const float* x          = (const float*)d_in[0];  // (16384,1024)
    const float* perm_logit = (const float*)d_in[1];  // (2,3)
    const float* abcd       = (const float*)d_in[2];  // (2,4092,2)
    const float* bias       = (const float*)d_in[3];  // (1024)
    float* out              = (float*)d_out;          // (16384,1024)

    __hip_bfloat16* Wt = (__hip_bfloat16*)d_ws;                      // 2 MB
    __hip_bfloat16* xb = (__hip_bfloat16*)((char*)d_ws + (1 << 21)); // 32 MB

    build_w<<<dim3(1024), dim3(256), 0, stream>>>(perm_logit, abcd, Wt);
    cast_x<<<dim3(8192), dim3(256), 0, stream>>>(x, xb);
    gemm_bt<<<dim3(1024), dim3(256), 0, stream>>>(xb, Wt, bias, out);
}

// Round 2
// 189.212 us; speedup vs baseline: 1.0502x; 1.0502x over previous
//
#include <hip/hip_runtime.h>
#include <hip/hip_bf16.h>
#include <stdint.h>

#define N_DIM 1024
#define DEPTH 2
#define ABCD_TOTAL 4092   // 2*(1024+512+...+2)

typedef __attribute__((ext_vector_type(8))) short short8;   // 8 bf16 (4 VGPRs)
typedef __attribute__((ext_vector_type(4))) float floatx4;  // MFMA accumulator

// ---------------------------------------------------------------------------
// Kernel 1 (fused): blocks [0,512) build W; blocks [512, 512+8192) cast x.
// Build: block b runs the linear butterfly pipeline on basis rows 2b, 2b+1.
// v_i = M[:, i]; stored COALESCED row-major: S[i*1024 + j] = v_i[j] (bf16).
// Cast blocks overlap their HBM-bound work with the latency-bound build.
// ---------------------------------------------------------------------------
__global__ __launch_bounds__(256) void build_and_cast(
    const float* __restrict__ perm_logit,  // (2,3)
    const float* __restrict__ abcd,        // (2,4092,2)
    const float* __restrict__ x,           // (16384,1024)
    __hip_bfloat16* __restrict__ S,        // (1024 i, 1024 j) = M[j,i], row-major
    __hip_bfloat16* __restrict__ xb)       // (16384,1024) bf16
{
    const int bx  = blockIdx.x;
    const int tid = threadIdx.x;
    __shared__ float2 h[2][2][N_DIM];  // [vec][pingpong][elem], 32 KB

    if (bx >= 512) {  // ---- cast part ----
        const int cb = bx - 512;
        const size_t i = ((size_t)cb * 256 + tid) * 8;
        float4 v0 = *(const float4*)(x + i);
        float4 v1 = *(const float4*)(x + i + 4);
        union { __hip_bfloat16 e[8]; int4 v; } u;
        u.e[0] = __float2bfloat16(v0.x); u.e[1] = __float2bfloat16(v0.y);
        u.e[2] = __float2bfloat16(v0.z); u.e[3] = __float2bfloat16(v0.w);
        u.e[4] = __float2bfloat16(v1.x); u.e[5] = __float2bfloat16(v1.y);
        u.e[6] = __float2bfloat16(v1.z); u.e[7] = __float2bfloat16(v1.w);
        *(int4*)(xb + i) = u.v;
        return;
    }

    // ---- build part: basis vectors row0, row0+1 ----
    const int row0 = bx * 2;
    const float2 zz = make_float2(0.0f, 0.0f);
    for (int j = tid; j < N_DIM; j += 256) {
        h[0][0][j] = zz; h[0][1][j] = zz;
        h[1][0][j] = zz; h[1][1][j] = zz;
    }
    __syncthreads();
    if (tid < 2) h[tid][0][row0 + tid] = make_float2(1.0f, 0.0f);
    __syncthreads();

    int cur = 0;
    for (int d = 0; d < DEPTH; ++d) {
        const float p0 = 1.0f / (1.0f + expf(-perm_logit[d * 3 + 0]));
        const float p1 = 1.0f / (1.0f + expf(-perm_logit[d * 3 + 1]));
        const float p2 = 1.0f / (1.0f + expf(-perm_logit[d * 3 + 2]));

        // ---- perm factors, m = 4 .. 1024 (ascending) ----
        for (int s = 2; s <= 10; ++s) {
            const int half = 1 << (s - 1), hq = half >> 1;
            // depth 0: support of e_row stays inside the 2^s block of row ->
            // only process that block's pairs (both rows share it for s>=1).
            // Skipped regions stay exactly zero (both buffers zero-inited).
            const int cnt   = (d == 0) ? half : 512;
            const int pbase = (d == 0) ? ((row0 >> s) << (s - 1)) : 0;
            for (int vt = tid; vt < 2 * cnt; vt += 256) {
                const int v = (vt < cnt) ? 0 : 1;
                const int t = pbase + (v ? vt - cnt : vt);
                const float2* __restrict__ in  = h[v][cur];
                float2* __restrict__ out       = h[v][cur ^ 1];
                const int blk  = t >> (s - 1);
                const int r    = t & (half - 1);
                const int base = blk << s;
                int q1, q2; float pc;
                if (r < hq) { q1 = r;           q2 = half - 1 - r;   pc = p1; }
                else        { int r2 = r - hq;  q1 = half + r2;
                              q2 = 2 * half - 1 - r2;                pc = p2; }
                const int src1 = (q1 < half) ? 2 * q1 : 2 * (q1 - half) + 1;
                const int src2 = (q2 < half) ? 2 * q2 : 2 * (q2 - half) + 1;
                float2 b1 = in[base + q1], a1 = in[base + src1];
                float2 b2 = in[base + q2], a2 = in[base + src2];
                float2 s1a, s1b, o1, o2;
                s1a.x = b1.x + p0 * (a1.x - b1.x);  s1a.y = b1.y + p0 * (a1.y - b1.y);
                s1b.x = b2.x + p0 * (a2.x - b2.x);  s1b.y = b2.y + p0 * (a2.y - b2.y);
                o1.x = s1a.x + pc * (s1b.x - s1a.x); o1.y = s1a.y + pc * (s1b.y - s1a.y);
                o2.x = s1b.x + pc * (s1a.x - s1b.x); o2.y = s1b.y + pc * (s1a.y - s1b.y);
                out[base + q1] = o1;
                out[base + q2] = o2;
            }
            __syncthreads();
            cur ^= 1;
        }

        // ---- diag factors, m = 2 .. 1024 (ascending) ----
        for (int s = 1; s <= 10; ++s) {
            const int m = 1 << s, half = m >> 1;
            const int off = 4096 - 4 * m;
            const float* __restrict__ ab = abcd + (size_t)d * (ABCD_TOTAL * 2) + (size_t)off * 2;
            for (int vt = tid; vt < 1024; vt += 256) {
                const int v = vt >> 9;
                const int t = vt & 511;
                const float2* __restrict__ in = h[v][cur];
                float2* __restrict__ out      = h[v][cur ^ 1];
                const int blk  = t >> (s - 1);
                const int k    = t & (half - 1);
                const int base = blk << s;
                float2 xt = in[base + k];
                float2 xb2 = in[base + half + k];
                float2 A  = *(const float2*)(ab + 2 * (size_t)k);
                float2 Bc = *(const float2*)(ab + 2 * (size_t)(half + k));
                float2 Cc = *(const float2*)(ab + 2 * (size_t)(m + k));
                float2 Dc = *(const float2*)(ab + 2 * (size_t)(m + half + k));
                float2 yt, yb;
                yt.x = A.x * xt.x - A.y * xt.y + Bc.x * xb2.x - Bc.y * xb2.y;
                yt.y = A.x * xt.y + A.y * xt.x + Bc.x * xb2.y + Bc.y * xb2.x;
                yb.x = Cc.x * xt.x - Cc.y * xt.y + Dc.x * xb2.x - Dc.y * xb2.y;
                yb.y = Cc.x * xt.y + Cc.y * xt.x + Dc.x * xb2.y + Dc.y * xb2.x;
                out[base + k]        = yt;
                out[base + half + k] = yb;
            }
            __syncthreads();
            cur ^= 1;
        }
    }

    // coalesced row-major store
    for (int j = tid; j < N_DIM; j += 256) {
        S[(size_t)row0 * N_DIM + j]       = __float2bfloat16(h[0][cur][j].x);
        S[(size_t)(row0 + 1) * N_DIM + j] = __float2bfloat16(h[1][cur][j].x);
    }
}

// ---------------------------------------------------------------------------
// Kernel 2: transpose S (i-major) -> Wt (j-major, contiguous k) via LDS tiles.
// Wt[j*1024 + i] = S[i*1024 + j].
// ---------------------------------------------------------------------------
__global__ __launch_bounds__(256) void transpose_w(
    const __hip_bfloat16* __restrict__ S, __hip_bfloat16* __restrict__ Wt)
{
    const int i0 = (blockIdx.x & 15) * 64;
    const int j0 = (blockIdx.x >> 4) * 64;
    __shared__ __hip_bfloat16 tile[64][72];  // 72*2=144 B rows (16B-aligned)
    const int r  = threadIdx.x >> 2;
    const int c0 = (threadIdx.x & 3) * 16;
    *(short8*)&tile[r][c0]     = *(const short8*)(S + (size_t)(i0 + r) * N_DIM + j0 + c0);
    *(short8*)&tile[r][c0 + 8] = *(const short8*)(S + (size_t)(i0 + r) * N_DIM + j0 + c0 + 8);
    __syncthreads();
    union { __hip_bfloat16 e[8]; short8 v; } o1, o2;
#pragma unroll
    for (int k = 0; k < 8; ++k) { o1.e[k] = tile[c0 + k][r]; o2.e[k] = tile[c0 + 8 + k][r]; }
    *(short8*)(Wt + (size_t)(j0 + r) * N_DIM + i0 + c0)     = o1.v;
    *(short8*)(Wt + (size_t)(j0 + r) * N_DIM + i0 + c0 + 8) = o2.v;
}

// ---------------------------------------------------------------------------
// Kernel 3: out = x(16384x1024 bf16) @ W + bias, fp32 out.
// 128x128 tile, BK=32, global_load_lds width 16, 16x16x32 bf16 MFMA.
// XCD swizzle: the 8 n-tiles of one m-tile land on ONE XCD (bx&7) so the
// shared A tile is fetched from HBM once, not 8x. XOR chunk swizzle
// (c ^= (row>>1)&3) spreads frag reads across banks (2-way max).
// ---------------------------------------------------------------------------
#define BM 128
#define BN 128
#define BK 32

__device__ __forceinline__ void gl_lds16(const void* g, void* l) {
    __builtin_amdgcn_global_load_lds(
        (const __attribute__((address_space(1))) uint32_t*)g,
        (__attribute__((address_space(3))) uint32_t*)l, 16, 0, 0);
}

__global__ __launch_bounds__(256) void gemm_bt(
    const __hip_bfloat16* __restrict__ A,   // (16384, 1024)
    const __hip_bfloat16* __restrict__ Bt,  // (1024 n, 1024 k)
    const float* __restrict__ bias,         // (1024)
    float* __restrict__ C)                  // (16384, 1024)
{
    const int tid = threadIdx.x;
    const int bx  = blockIdx.x;
    // XCD-aware: xcd = bx&7 owns m-tiles [xcd*16, xcd*16+16), all 8 n-tiles
    const int xcd = bx & 7;
    const int loc = bx >> 3;                  // 0..127
    const int m0  = (xcd * 16 + (loc >> 3)) * BM;
    const int n0  = (loc & 7) * BN;

    __shared__ __hip_bfloat16 sA[BM * BK];  // 8 KB
    __shared__ __hip_bfloat16 sB[BN * BK];  // 8 KB

    const int lane = tid & 63;
    const int wm   = ((tid >> 6) & 1) * 64;
    const int wn   = ((tid >> 6) >> 1) * 64;
    const int lrow = lane & 15;
    const int lq   = lane >> 4;

    // staging granule g: row = g>>2, global 16B-chunk c = (g&3) ^ ((g>>3)&3)
    const int r1  = tid >> 2;
    const int c1s = (tid & 3) ^ ((tid >> 3) & 3);
    // frag-read chunk: lq ^ ((row>>1)&3); (row>>1)&3 == (lrow>>1)&3 (bases %16==0)
    const int swz = (lrow >> 1) & 3;
    const int ca  = lq ^ swz;

    floatx4 acc[4][4] = {};

    for (int kt = 0; kt < 32; ++kt) {
        const int k0 = kt * BK;
        gl_lds16(A  + (size_t)(m0 + r1)      * N_DIM + k0 + c1s * 8, (char*)sA + tid * 16);
        gl_lds16(A  + (size_t)(m0 + 64 + r1) * N_DIM + k0 + c1s * 8, (char*)sA + (tid + 256) * 16);
        gl_lds16(Bt + (size_t)(n0 + r1)      * N_DIM + k0 + c1s * 8, (char*)sB + tid * 16);
        gl_lds16(Bt + (size_t)(n0 + 64 + r1) * N_DIM + k0 + c1s * 8, (char*)sB + (tid + 256) * 16);
        __syncthreads();

        short8 af[4], bf[4];
#pragma unroll
        for (int i = 0; i < 4; ++i) {
            af[i] = *(const short8*)((const char*)sA + ((wm + i * 16 + lrow) * 4 + ca) * 16);
            bf[i] = *(const short8*)((const char*)sB + ((wn + i * 16 + lrow) * 4 + ca) * 16);
        }
#pragma unroll
        for (int i = 0; i < 4; ++i)
#pragma unroll
            for (int j = 0; j < 4; ++j)
                acc[i][j] = __builtin_amdgcn_mfma_f32_16x16x32_bf16(
                    af[i], bf[j], acc[i][j], 0, 0, 0);
        __syncthreads();
    }

#pragma unroll
    for (int j = 0; j < 4; ++j) {
        const int gn = n0 + wn + j * 16 + lrow;
        const float bv = bias[gn];
#pragma unroll
        for (int i = 0; i < 4; ++i) {
            const int gm = m0 + wm + i * 16 + lq * 4;
#pragma unroll
            for (int r = 0; r < 4; ++r)
                C[(size_t)(gm + r) * N_DIM + gn] = acc[i][j][r] + bv;
        }
    }
}

// ---------------------------------------------------------------------------
extern "C" void kernel_launch(void* const* d_in, const int* in_sizes, int n_in,
                              void* d_out, int out_size, void* d_ws, size_t ws_size,
                              hipStream_t stream) {
    const float* x          = (const float*)d_in[0];
    const float* perm_logit = (const float*)d_in[1];
    const float* abcd       = (const float*)d_in[2];
    const float* bias       = (const float*)d_in[3];
    float* out              = (float*)d_out;

    // S (2 MB) lives in d_out scratch space (gemm overwrites d_out afterward).
    __hip_bfloat16* S  = (__hip_bfloat16*)d_out;
    __hip_bfloat16* Wt = (__hip_bfloat16*)d_ws;                      // 2 MB
    __hip_bfloat16* xb = (__hip_bfloat16*)((char*)d_ws + (1 << 21)); // 32 MB

    build_and_cast<<<dim3(512 + 8192), dim3(256), 0, stream>>>(perm_logit, abcd, x, S, xb);
    transpose_w<<<dim3(256), dim3(256), 0, stream>>>(S, Wt);
    gemm_bt<<<dim3(1024), dim3(256), 0, stream>>>(xb, Wt, bias, out);
}

// Round 3
// 164.803 us; speedup vs baseline: 1.2057x; 1.1481x over previous
//
#include <hip/hip_runtime.h>
#include <hip/hip_bf16.h>
#include <stdint.h>

#define N_DIM 1024
#define DEPTH 2
#define ABCD_TOTAL 4092   // 2*(1024+512+...+2)

typedef __attribute__((ext_vector_type(8))) short short8;   // 8 bf16 (4 VGPRs)
typedef __attribute__((ext_vector_type(4))) float floatx4;  // MFMA accumulator
typedef __attribute__((ext_vector_type(4))) float f4;       // {re0,im0,re1,im1}

// complex (cr,ci) times interleaved pair-vector v
__device__ __forceinline__ f4 cmul(float cr, float ci, f4 v) {
    f4 r;
    r[0] = cr * v[0] - ci * v[1];
    r[1] = cr * v[1] + ci * v[0];
    r[2] = cr * v[2] - ci * v[3];
    r[3] = cr * v[3] + ci * v[2];
    return r;
}

// ---------------------------------------------------------------------------
// Kernel 1 (fused): blocks [0,512) build W; blocks [512, 512+8192) cast x.
// Build: block b propagates basis vectors 2b, 2b+1 through the (linear)
// pipeline, INTERLEAVED as one f4 per element -> all LDS ops are b128 and
// index math is shared. Diag stages are fused in pairs (s,s+1): the 4-point
// group {k, k+h, k+2h, k+3h} is closed under both stages.
// S[i*1024 + j] = v_i[j] (coalesced row-major bf16).
// ---------------------------------------------------------------------------
__global__ __launch_bounds__(256) void build_and_cast(
    const float* __restrict__ perm_logit,  // (2,3)
    const float* __restrict__ abcd,        // (2,4092,2)
    const float* __restrict__ x,           // (16384,1024)
    __hip_bfloat16* __restrict__ S,        // (1024 i, 1024 j)
    __hip_bfloat16* __restrict__ xb)       // (16384,1024) bf16
{
    const int bx  = blockIdx.x;
    const int tid = threadIdx.x;
    __shared__ f4 h[2][N_DIM];  // ping-pong interleaved buffers, 32 KB

    if (bx >= 512) {  // ---- cast part ----
        const int cb = bx - 512;
        const size_t i = ((size_t)cb * 256 + tid) * 8;
        float4 v0 = *(const float4*)(x + i);
        float4 v1 = *(const float4*)(x + i + 4);
        union { __hip_bfloat16 e[8]; int4 v; } u;
        u.e[0] = __float2bfloat16(v0.x); u.e[1] = __float2bfloat16(v0.y);
        u.e[2] = __float2bfloat16(v0.z); u.e[3] = __float2bfloat16(v0.w);
        u.e[4] = __float2bfloat16(v1.x); u.e[5] = __float2bfloat16(v1.y);
        u.e[6] = __float2bfloat16(v1.z); u.e[7] = __float2bfloat16(v1.w);
        *(int4*)(xb + i) = u.v;
        return;
    }

    // ---- build part ----
    const int row0 = bx * 2;
    const f4 zz = {0.0f, 0.0f, 0.0f, 0.0f};
    for (int j = tid; j < N_DIM; j += 256) { h[0][j] = zz; h[1][j] = zz; }
    __syncthreads();
    if (tid == 0) {
        f4 e0 = {1.0f, 0.0f, 0.0f, 0.0f};
        f4 e1 = {0.0f, 0.0f, 1.0f, 0.0f};
        h[0][row0]     = e0;
        h[0][row0 + 1] = e1;
    }
    __syncthreads();

    int cur = 0;
    for (int d = 0; d < DEPTH; ++d) {
        const float p0 = 1.0f / (1.0f + expf(-perm_logit[d * 3 + 0]));
        const float p1 = 1.0f / (1.0f + expf(-perm_logit[d * 3 + 1]));
        const float p2 = 1.0f / (1.0f + expf(-perm_logit[d * 3 + 2]));

        // ---- perm factors, m = 4 .. 1024 (ascending) ----
#pragma unroll
        for (int s = 2; s <= 10; ++s) {
            const int half = 1 << (s - 1), hq = half >> 1;
            // depth 0: support confined to the 2^s block containing row0;
            // untouched regions of both buffers remain exactly zero.
            const int cnt   = (d == 0) ? half : 512;
            const int pbase = (d == 0) ? ((row0 >> s) << (s - 1)) : 0;
            const f4* __restrict__ in = h[cur];
            f4* __restrict__ out      = h[cur ^ 1];
            for (int tt = tid; tt < cnt; tt += 256) {
                const int t    = pbase + tt;
                const int blk  = t >> (s - 1);
                const int r    = t & (half - 1);
                const int base = blk << s;
                int q1, q2; float pc;
                if (r < hq) { q1 = r;           q2 = half - 1 - r;   pc = p1; }
                else        { int r2 = r - hq;  q1 = half + r2;
                              q2 = 2 * half - 1 - r2;                pc = p2; }
                const int src1 = (q1 < half) ? 2 * q1 : 2 * (q1 - half) + 1;
                const int src2 = (q2 < half) ? 2 * q2 : 2 * (q2 - half) + 1;
                f4 b1 = in[base + q1], a1 = in[base + src1];
                f4 b2 = in[base + q2], a2 = in[base + src2];
                f4 s1a = b1 + p0 * (a1 - b1);
                f4 s1b = b2 + p0 * (a2 - b2);
                out[base + q1] = s1a + pc * (s1b - s1a);
                out[base + q2] = s1b + pc * (s1a - s1b);
            }
            __syncthreads();
            cur ^= 1;
        }

        // ---- diag factors fused in pairs: (1,2),(3,4),(5,6),(7,8),(9,10) ----
        const float* __restrict__ abd = abcd + (size_t)d * (ABCD_TOTAL * 2);
#pragma unroll
        for (int s = 1; s <= 9; s += 2) {
            const int hh = 1 << (s - 1);                 // half of stage s
            const float* __restrict__ ab1 = abd + (size_t)(4096 - 8 * hh) * 2;
            const float* __restrict__ ab2 = abd + (size_t)(4096 - 16 * hh) * 2;
            const f4* __restrict__ in = h[cur];
            f4* __restrict__ out      = h[cur ^ 1];
            {
                const int g     = tid;                   // 256 groups of 4
                const int k     = g & (hh - 1);
                const int base2 = (g >> (s - 1)) << (s + 1);
                f4 x0 = in[base2 + k];
                f4 x1 = in[base2 + k + hh];
                f4 x2 = in[base2 + k + 2 * hh];
                f4 x3 = in[base2 + k + 3 * hh];
                // stage s: pairs (x0,x1), (x2,x3); same ABCD[k] for both
                float2 A = *(const float2*)(ab1 + 2 * (size_t)k);
                float2 B = *(const float2*)(ab1 + 2 * (size_t)(hh + k));
                float2 C = *(const float2*)(ab1 + 2 * (size_t)(2 * hh + k));
                float2 D = *(const float2*)(ab1 + 2 * (size_t)(3 * hh + k));
                f4 y0 = cmul(A.x, A.y, x0) + cmul(B.x, B.y, x1);
                f4 y1 = cmul(C.x, C.y, x0) + cmul(D.x, D.y, x1);
                f4 y2 = cmul(A.x, A.y, x2) + cmul(B.x, B.y, x3);
                f4 y3 = cmul(C.x, C.y, x2) + cmul(D.x, D.y, x3);
                // stage s+1: pairs (y0,y2) at k2=k, (y1,y3) at k2=k+hh
                float2 A2 = *(const float2*)(ab2 + 2 * (size_t)k);
                float2 B2 = *(const float2*)(ab2 + 2 * (size_t)(2 * hh + k));
                float2 C2 = *(const float2*)(ab2 + 2 * (size_t)(4 * hh + k));
                float2 D2 = *(const float2*)(ab2 + 2 * (size_t)(6 * hh + k));
                float2 A3 = *(const float2*)(ab2 + 2 * (size_t)(hh + k));
                float2 B3 = *(const float2*)(ab2 + 2 * (size_t)(3 * hh + k));
                float2 C3 = *(const float2*)(ab2 + 2 * (size_t)(5 * hh + k));
                float2 D3 = *(const float2*)(ab2 + 2 * (size_t)(7 * hh + k));
                out[base2 + k]          = cmul(A2.x, A2.y, y0) + cmul(B2.x, B2.y, y2);
                out[base2 + k + 2 * hh] = cmul(C2.x, C2.y, y0) + cmul(D2.x, D2.y, y2);
                out[base2 + k + hh]     = cmul(A3.x, A3.y, y1) + cmul(B3.x, B3.y, y3);
                out[base2 + k + 3 * hh] = cmul(C3.x, C3.y, y1) + cmul(D3.x, D3.y, y3);
            }
            __syncthreads();
            cur ^= 1;
        }
    }

    // coalesced row-major store of the two real parts
    for (int j = tid; j < N_DIM; j += 256) {
        f4 v = h[cur][j];
        S[(size_t)row0 * N_DIM + j]       = __float2bfloat16(v[0]);
        S[(size_t)(row0 + 1) * N_DIM + j] = __float2bfloat16(v[2]);
    }
}

// ---------------------------------------------------------------------------
// Kernel 2: transpose S (i-major) -> Wt (j-major, contiguous k) via LDS tiles.
// ---------------------------------------------------------------------------
__global__ __launch_bounds__(256) void transpose_w(
    const __hip_bfloat16* __restrict__ S, __hip_bfloat16* __restrict__ Wt)
{
    const int i0 = (blockIdx.x & 15) * 64;
    const int j0 = (blockIdx.x >> 4) * 64;
    __shared__ __hip_bfloat16 tile[64][72];
    const int r  = threadIdx.x >> 2;
    const int c0 = (threadIdx.x & 3) * 16;
    *(short8*)&tile[r][c0]     = *(const short8*)(S + (size_t)(i0 + r) * N_DIM + j0 + c0);
    *(short8*)&tile[r][c0 + 8] = *(const short8*)(S + (size_t)(i0 + r) * N_DIM + j0 + c0 + 8);
    __syncthreads();
    union { __hip_bfloat16 e[8]; short8 v; } o1, o2;
#pragma unroll
    for (int k = 0; k < 8; ++k) { o1.e[k] = tile[c0 + k][r]; o2.e[k] = tile[c0 + 8 + k][r]; }
    *(short8*)(Wt + (size_t)(j0 + r) * N_DIM + i0 + c0)     = o1.v;
    *(short8*)(Wt + (size_t)(j0 + r) * N_DIM + i0 + c0 + 8) = o2.v;
}

// ---------------------------------------------------------------------------
// Kernel 3: out = x(16384x1024 bf16) @ W + bias, fp32 out.
// 128x128 tile, BK=32, global_load_lds width 16, 16x16x32 bf16 MFMA.
// XCD swizzle keeps all 8 n-tiles of an m-tile on one XCD (FETCH at ideal).
// XOR chunk swizzle keeps LDS conflict-free (measured 0 last round).
// ---------------------------------------------------------------------------
#define BM 128
#define BN 128
#define BK 32

__device__ __forceinline__ void gl_lds16(const void* g, void* l) {
    __builtin_amdgcn_global_load_lds(
        (const __attribute__((address_space(1))) uint32_t*)g,
        (__attribute__((address_space(3))) uint32_t*)l, 16, 0, 0);
}

__global__ __launch_bounds__(256) void gemm_bt(
    const __hip_bfloat16* __restrict__ A,   // (16384, 1024)
    const __hip_bfloat16* __restrict__ Bt,  // (1024 n, 1024 k)
    const float* __restrict__ bias,         // (1024)
    float* __restrict__ C)                  // (16384, 1024)
{
    const int tid = threadIdx.x;
    const int bx  = blockIdx.x;
    const int xcd = bx & 7;
    const int loc = bx >> 3;
    const int m0  = (xcd * 16 + (loc >> 3)) * BM;
    const int n0  = (loc & 7) * BN;

    __shared__ __hip_bfloat16 sA[BM * BK];
    __shared__ __hip_bfloat16 sB[BN * BK];

    const int lane = tid & 63;
    const int wm   = ((tid >> 6) & 1) * 64;
    const int wn   = ((tid >> 6) >> 1) * 64;
    const int lrow = lane & 15;
    const int lq   = lane >> 4;

    const int r1  = tid >> 2;
    const int c1s = (tid & 3) ^ ((tid >> 3) & 3);
    const int swz = (lrow >> 1) & 3;
    const int ca  = lq ^ swz;

    floatx4 acc[4][4] = {};

    for (int kt = 0; kt < 32; ++kt) {
        const int k0 = kt * BK;
        gl_lds16(A  + (size_t)(m0 + r1)      * N_DIM + k0 + c1s * 8, (char*)sA + tid * 16);
        gl_lds16(A  + (size_t)(m0 + 64 + r1) * N_DIM + k0 + c1s * 8, (char*)sA + (tid + 256) * 16);
        gl_lds16(Bt + (size_t)(n0 + r1)      * N_DIM + k0 + c1s * 8, (char*)sB + tid * 16);
        gl_lds16(Bt + (size_t)(n0 + 64 + r1) * N_DIM + k0 + c1s * 8, (char*)sB + (tid + 256) * 16);
        __syncthreads();

        short8 af[4], bf[4];
#pragma unroll
        for (int i = 0; i < 4; ++i) {
            af[i] = *(const short8*)((const char*)sA + ((wm + i * 16 + lrow) * 4 + ca) * 16);
            bf[i] = *(const short8*)((const char*)sB + ((wn + i * 16 + lrow) * 4 + ca) * 16);
        }
#pragma unroll
        for (int i = 0; i < 4; ++i)
#pragma unroll
            for (int j = 0; j < 4; ++j)
                acc[i][j] = __builtin_amdgcn_mfma_f32_16x16x32_bf16(
                    af[i], bf[j], acc[i][j], 0, 0, 0);
        __syncthreads();
    }

#pragma unroll
    for (int j = 0; j < 4; ++j) {
        const int gn = n0 + wn + j * 16 + lrow;
        const float bv = bias[gn];
#pragma unroll
        for (int i = 0; i < 4; ++i) {
            const int gm = m0 + wm + i * 16 + lq * 4;
#pragma unroll
            for (int r = 0; r < 4; ++r)
                C[(size_t)(gm + r) * N_DIM + gn] = acc[i][j][r] + bv;
        }
    }
}

// ---------------------------------------------------------------------------
extern "C" void kernel_launch(void* const* d_in, const int* in_sizes, int n_in,
                              void* d_out, int out_size, void* d_ws, size_t ws_size,
                              hipStream_t stream) {
    const float* x          = (const float*)d_in[0];
    const float* perm_logit = (const float*)d_in[1];
    const float* abcd       = (const float*)d_in[2];
    const float* bias       = (const float*)d_in[3];
    float* out              = (float*)d_out;

    // S (2 MB) lives in d_out scratch space (gemm overwrites d_out afterward).
    __hip_bfloat16* S  = (__hip_bfloat16*)d_out;
    __hip_bfloat16* Wt = (__hip_bfloat16*)d_ws;                      // 2 MB
    __hip_bfloat16* xb = (__hip_bfloat16*)((char*)d_ws + (1 << 21)); // 32 MB

    build_and_cast<<<dim3(512 + 8192), dim3(256), 0, stream>>>(perm_logit, abcd, x, S, xb);
    transpose_w<<<dim3(256), dim3(256), 0, stream>>>(S, Wt);
    gemm_bt<<<dim3(1024), dim3(256), 0, stream>>>(xb, Wt, bias, out);
}

// Round 4
// 155.901 us; speedup vs baseline: 1.2746x; 1.0571x over previous
//
#include <hip/hip_runtime.h>
#include <hip/hip_bf16.h>
#include <stdint.h>

#define N_DIM 1024
#define DEPTH 2
#define ABCD_TOTAL 4092   // 2*(1024+512+...+2)

typedef __attribute__((ext_vector_type(8))) short short8;   // 8 bf16 (4 VGPRs)
typedef __attribute__((ext_vector_type(4))) float floatx4;  // MFMA accumulator
typedef __attribute__((ext_vector_type(4))) float f4;       // {re0,im0,re1,im1}

__device__ __forceinline__ f4 cmul(float cr, float ci, f4 v) {
    f4 r;
    r[0] = cr * v[0] - ci * v[1];
    r[1] = cr * v[1] + ci * v[0];
    r[2] = cr * v[2] - ci * v[3];
    r[3] = cr * v[3] + ci * v[2];
    return r;
}

// ---------------------------------------------------------------------------
// Kernel 1 (fused): blocks [0,512) build W; blocks [512, 512+8192) cast x.
// Wave-synchronous stages: perm s<=7 and diag pairs (1,2)..(7,8) are closed
// within one wave's LDS span (verified footprint: perm wave w touches
// [128w,+128) u [512+128w,+128) for every s<=7; diag wave w touches
// [256w,+256) for every pair; depth-0 small stages live in wave 0 only).
// DS ops within a wave execute in order -> only a compiler ordering barrier
// (__builtin_amdgcn_wave_barrier) is needed there. Full __syncthreads only
// before perm s=8,9,10, after perm 10, and around diag pair (9,10):
// 14 barriers instead of 28.
// ---------------------------------------------------------------------------
__global__ __launch_bounds__(256) void build_and_cast(
    const float* __restrict__ perm_logit,  // (2,3)
    const float* __restrict__ abcd,        // (2,4092,2)
    const float* __restrict__ x,           // (16384,1024)
    __hip_bfloat16* __restrict__ S,        // (1024 i, 1024 j)
    __hip_bfloat16* __restrict__ xb)       // (16384,1024) bf16
{
    const int bx  = blockIdx.x;
    const int tid = threadIdx.x;
    __shared__ f4 h[2][N_DIM];  // ping-pong interleaved buffers, 32 KB

    if (bx >= 512) {  // ---- cast part ----
        const int cb = bx - 512;
        const size_t i = ((size_t)cb * 256 + tid) * 8;
        float4 v0 = *(const float4*)(x + i);
        float4 v1 = *(const float4*)(x + i + 4);
        union { __hip_bfloat16 e[8]; int4 v; } u;
        u.e[0] = __float2bfloat16(v0.x); u.e[1] = __float2bfloat16(v0.y);
        u.e[2] = __float2bfloat16(v0.z); u.e[3] = __float2bfloat16(v0.w);
        u.e[4] = __float2bfloat16(v1.x); u.e[5] = __float2bfloat16(v1.y);
        u.e[6] = __float2bfloat16(v1.z); u.e[7] = __float2bfloat16(v1.w);
        *(int4*)(xb + i) = u.v;
        return;
    }

    // ---- build part ----
    const int row0 = bx * 2;
    const f4 zz = {0.0f, 0.0f, 0.0f, 0.0f};
    for (int j = tid; j < N_DIM; j += 256) { h[0][j] = zz; h[1][j] = zz; }
    __syncthreads();
    if (tid == 0) {
        f4 e0 = {1.0f, 0.0f, 0.0f, 0.0f};
        f4 e1 = {0.0f, 0.0f, 1.0f, 0.0f};
        h[0][row0]     = e0;
        h[0][row0 + 1] = e1;
    }
    __syncthreads();

    int cur = 0;
    for (int d = 0; d < DEPTH; ++d) {
        const float p0 = 1.0f / (1.0f + expf(-perm_logit[d * 3 + 0]));
        const float p1 = 1.0f / (1.0f + expf(-perm_logit[d * 3 + 1]));
        const float p2 = 1.0f / (1.0f + expf(-perm_logit[d * 3 + 2]));

        // ---- perm factors, m = 4 .. 1024 (ascending) ----
#pragma unroll
        for (int s = 2; s <= 10; ++s) {
            if (s >= 8) __syncthreads();             // cross-wave mixing starts
            else        __builtin_amdgcn_wave_barrier();
            const int half = 1 << (s - 1), hq = half >> 1;
            const int cnt   = (d == 0) ? half : 512;
            const int pbase = (d == 0) ? ((row0 >> s) << (s - 1)) : 0;
            const f4* __restrict__ in = h[cur];
            f4* __restrict__ out      = h[cur ^ 1];
            for (int tt = tid; tt < cnt; tt += 256) {
                const int t    = pbase + tt;
                const int blk  = t >> (s - 1);
                const int r    = t & (half - 1);
                const int base = blk << s;
                int q1, q2; float pc;
                if (r < hq) { q1 = r;           q2 = half - 1 - r;   pc = p1; }
                else        { int r2 = r - hq;  q1 = half + r2;
                              q2 = 2 * half - 1 - r2;                pc = p2; }
                const int src1 = (q1 < half) ? 2 * q1 : 2 * (q1 - half) + 1;
                const int src2 = (q2 < half) ? 2 * q2 : 2 * (q2 - half) + 1;
                f4 b1 = in[base + q1], a1 = in[base + src1];
                f4 b2 = in[base + q2], a2 = in[base + src2];
                f4 s1a = b1 + p0 * (a1 - b1);
                f4 s1b = b2 + p0 * (a2 - b2);
                out[base + q1] = s1a + pc * (s1b - s1a);
                out[base + q2] = s1b + pc * (s1a - s1b);
            }
            cur ^= 1;
        }
        __syncthreads();  // perm s=10 output is block-wide

        // ---- diag factors fused in pairs: (1,2)..(9,10) ----
        const float* __restrict__ abd = abcd + (size_t)d * (ABCD_TOTAL * 2);
#pragma unroll
        for (int s = 1; s <= 9; s += 2) {
            if (s == 9) __syncthreads();             // (9,10) mixes across waves
            else        __builtin_amdgcn_wave_barrier();
            const int hh = 1 << (s - 1);
            const float* __restrict__ ab1 = abd + (size_t)(4096 - 8 * hh) * 2;
            const float* __restrict__ ab2 = abd + (size_t)(4096 - 16 * hh) * 2;
            const f4* __restrict__ in = h[cur];
            f4* __restrict__ out      = h[cur ^ 1];
            {
                const int g     = tid;
                const int k     = g & (hh - 1);
                const int base2 = (g >> (s - 1)) << (s + 1);
                f4 x0 = in[base2 + k];
                f4 x1 = in[base2 + k + hh];
                f4 x2 = in[base2 + k + 2 * hh];
                f4 x3 = in[base2 + k + 3 * hh];
                float2 A = *(const float2*)(ab1 + 2 * (size_t)k);
                float2 B = *(const float2*)(ab1 + 2 * (size_t)(hh + k));
                float2 C = *(const float2*)(ab1 + 2 * (size_t)(2 * hh + k));
                float2 D = *(const float2*)(ab1 + 2 * (size_t)(3 * hh + k));
                f4 y0 = cmul(A.x, A.y, x0) + cmul(B.x, B.y, x1);
                f4 y1 = cmul(C.x, C.y, x0) + cmul(D.x, D.y, x1);
                f4 y2 = cmul(A.x, A.y, x2) + cmul(B.x, B.y, x3);
                f4 y3 = cmul(C.x, C.y, x2) + cmul(D.x, D.y, x3);
                float2 A2 = *(const float2*)(ab2 + 2 * (size_t)k);
                float2 B2 = *(const float2*)(ab2 + 2 * (size_t)(2 * hh + k));
                float2 C2 = *(const float2*)(ab2 + 2 * (size_t)(4 * hh + k));
                float2 D2 = *(const float2*)(ab2 + 2 * (size_t)(6 * hh + k));
                float2 A3 = *(const float2*)(ab2 + 2 * (size_t)(hh + k));
                float2 B3 = *(const float2*)(ab2 + 2 * (size_t)(3 * hh + k));
                float2 C3 = *(const float2*)(ab2 + 2 * (size_t)(5 * hh + k));
                float2 D3 = *(const float2*)(ab2 + 2 * (size_t)(7 * hh + k));
                out[base2 + k]          = cmul(A2.x, A2.y, y0) + cmul(B2.x, B2.y, y2);
                out[base2 + k + 2 * hh] = cmul(C2.x, C2.y, y0) + cmul(D2.x, D2.y, y2);
                out[base2 + k + hh]     = cmul(A3.x, A3.y, y1) + cmul(B3.x, B3.y, y3);
                out[base2 + k + 3 * hh] = cmul(C3.x, C3.y, y1) + cmul(D3.x, D3.y, y3);
            }
            cur ^= 1;
        }
        __syncthreads();  // (9,10) output is block-wide
    }

    for (int j = tid; j < N_DIM; j += 256) {
        f4 v = h[cur][j];
        S[(size_t)row0 * N_DIM + j]       = __float2bfloat16(v[0]);
        S[(size_t)(row0 + 1) * N_DIM + j] = __float2bfloat16(v[2]);
    }
}

// ---------------------------------------------------------------------------
// Kernel 2: transpose S (i-major) -> Wt (j-major, contiguous k) via LDS tiles.
// ---------------------------------------------------------------------------
__global__ __launch_bounds__(256) void transpose_w(
    const __hip_bfloat16* __restrict__ S, __hip_bfloat16* __restrict__ Wt)
{
    const int i0 = (blockIdx.x & 15) * 64;
    const int j0 = (blockIdx.x >> 4) * 64;
    __shared__ __hip_bfloat16 tile[64][72];
    const int r  = threadIdx.x >> 2;
    const int c0 = (threadIdx.x & 3) * 16;
    *(short8*)&tile[r][c0]     = *(const short8*)(S + (size_t)(i0 + r) * N_DIM + j0 + c0);
    *(short8*)&tile[r][c0 + 8] = *(const short8*)(S + (size_t)(i0 + r) * N_DIM + j0 + c0 + 8);
    __syncthreads();
    union { __hip_bfloat16 e[8]; short8 v; } o1, o2;
#pragma unroll
    for (int k = 0; k < 8; ++k) { o1.e[k] = tile[c0 + k][r]; o2.e[k] = tile[c0 + 8 + k][r]; }
    *(short8*)(Wt + (size_t)(j0 + r) * N_DIM + i0 + c0)     = o1.v;
    *(short8*)(Wt + (size_t)(j0 + r) * N_DIM + i0 + c0 + 8) = o2.v;
}

// ---------------------------------------------------------------------------
// Kernel 3: out = x(16384x1024 bf16) @ W + bias, fp32 out.
// 128x128 tile, BK=64 (16 K-iters -> 32 barrier drains instead of 64),
// global_load_lds width 16, 16x16x32 bf16 MFMA, XCD-aware block swizzle.
// Row stride in LDS is 128 B = 32 banks, so chunk swizzle c^=(row&7) is
// applied on the GLOBAL address side (LDS side must stay lane-contiguous
// for global_load_lds); frag reads then hit 2-way banks (free).
// ---------------------------------------------------------------------------
#define BM 128
#define BN 128
#define BK 64

__device__ __forceinline__ void gl_lds16(const void* g, void* l) {
    __builtin_amdgcn_global_load_lds(
        (const __attribute__((address_space(1))) uint32_t*)g,
        (__attribute__((address_space(3))) uint32_t*)l, 16, 0, 0);
}

__global__ __launch_bounds__(256, 4) void gemm_bt(
    const __hip_bfloat16* __restrict__ A,   // (16384, 1024)
    const __hip_bfloat16* __restrict__ Bt,  // (1024 n, 1024 k)
    const float* __restrict__ bias,         // (1024)
    float* __restrict__ C)                  // (16384, 1024)
{
    const int tid = threadIdx.x;
    const int bx  = blockIdx.x;
    const int xcd = bx & 7;
    const int loc = bx >> 3;
    const int m0  = (xcd * 16 + (loc >> 3)) * BM;
    const int n0  = (loc & 7) * BN;

    __shared__ __hip_bfloat16 sA[BM * BK];  // 16 KB
    __shared__ __hip_bfloat16 sB[BN * BK];  // 16 KB

    const int lane = tid & 63;
    const int wm   = ((tid >> 6) & 1) * 64;
    const int wn   = ((tid >> 6) >> 1) * 64;
    const int lrow = lane & 15;
    const int lq   = lane >> 4;

    // staging: granule g = tid + i*256; row = g>>3 = r1 + i*32, chunk = g&7.
    // global chunk swizzled: cs = c1 ^ (row&7); (r1+i*32)&7 == r1&7.
    const int r1 = tid >> 3;
    const int cs = (tid & 7) ^ (r1 & 7);
    const int swz = lrow & 7;

    floatx4 acc[4][4] = {};

    for (int kt = 0; kt < 16; ++kt) {
        const int k0 = kt * BK;
#pragma unroll
        for (int i = 0; i < 4; ++i)
            gl_lds16(A + (size_t)(m0 + r1 + i * 32) * N_DIM + k0 + cs * 8,
                     (char*)sA + (tid + i * 256) * 16);
#pragma unroll
        for (int i = 0; i < 4; ++i)
            gl_lds16(Bt + (size_t)(n0 + r1 + i * 32) * N_DIM + k0 + cs * 8,
                     (char*)sB + (tid + i * 256) * 16);
        __syncthreads();

#pragma unroll
        for (int ks = 0; ks < 2; ++ks) {
            short8 af[4], bf[4];
            const int cc = (lq + 4 * ks) ^ swz;
#pragma unroll
            for (int i = 0; i < 4; ++i) {
                af[i] = *(const short8*)((const char*)sA + (((wm + i * 16 + lrow) * 8 + cc) * 16));
                bf[i] = *(const short8*)((const char*)sB + (((wn + i * 16 + lrow) * 8 + cc) * 16));
            }
#pragma unroll
            for (int i = 0; i < 4; ++i)
#pragma unroll
                for (int j = 0; j < 4; ++j)
                    acc[i][j] = __builtin_amdgcn_mfma_f32_16x16x32_bf16(
                        af[i], bf[j], acc[i][j], 0, 0, 0);
        }
        __syncthreads();
    }

#pragma unroll
    for (int j = 0; j < 4; ++j) {
        const int gn = n0 + wn + j * 16 + lrow;
        const float bv = bias[gn];
#pragma unroll
        for (int i = 0; i < 4; ++i) {
            const int gm = m0 + wm + i * 16 + lq * 4;
#pragma unroll
            for (int r = 0; r < 4; ++r)
                C[(size_t)(gm + r) * N_DIM + gn] = acc[i][j][r] + bv;
        }
    }
}

// ---------------------------------------------------------------------------
extern "C" void kernel_launch(void* const* d_in, const int* in_sizes, int n_in,
                              void* d_out, int out_size, void* d_ws, size_t ws_size,
                              hipStream_t stream) {
    const float* x          = (const float*)d_in[0];
    const float* perm_logit = (const float*)d_in[1];
    const float* abcd       = (const float*)d_in[2];
    const float* bias       = (const float*)d_in[3];
    float* out              = (float*)d_out;

    // S (2 MB) lives in d_out scratch space (gemm overwrites d_out afterward).
    __hip_bfloat16* S  = (__hip_bfloat16*)d_out;
    __hip_bfloat16* Wt = (__hip_bfloat16*)d_ws;                      // 2 MB
    __hip_bfloat16* xb = (__hip_bfloat16*)((char*)d_ws + (1 << 21)); // 32 MB

    build_and_cast<<<dim3(512 + 8192), dim3(256), 0, stream>>>(perm_logit, abcd, x, S, xb);
    transpose_w<<<dim3(256), dim3(256), 0, stream>>>(S, Wt);
    gemm_bt<<<dim3(1024), dim3(256), 0, stream>>>(xb, Wt, bias, out);
}